// Round 5
// baseline (347.598 us; speedup 1.0000x reference)
//
#include <hip/hip_runtime.h>

// Window MHA: B=16, H=W=64, C=512, WS=8, NH=16, hd=32. f32 I/O.
// Pipeline per chunk: conv_permute_x (f32->bf16 + window partition) ->
// QKV GEMM (8-phase 256^2) -> attn -> proj GEMM (8-phase, f32 out + reverse).

typedef unsigned short u16;
typedef unsigned int u32;
typedef __attribute__((ext_vector_type(8))) u16 u16x8;
typedef __attribute__((ext_vector_type(8))) short short8;
typedef __attribute__((ext_vector_type(4))) float f32x4;

__device__ __forceinline__ u16 f2bf(float f) {
    u32 u = __float_as_uint(f);
    u += 0x7fffu + ((u >> 16) & 1u);   // RNE
    return (u16)(u >> 16);
}

__device__ __forceinline__ f32x4 MFMA(u16x8 a, u16x8 b, f32x4 c) {
    return __builtin_amdgcn_mfma_f32_16x16x32_bf16(
        __builtin_bit_cast(short8, a), __builtin_bit_cast(short8, b), c, 0, 0, 0);
}

__device__ __forceinline__ void gload16(const void* g, void* l) {
    __builtin_amdgcn_global_load_lds(
        (const __attribute__((address_space(1))) void*)g,
        (__attribute__((address_space(3))) void*)l, 16, 0, 0);
}

// chunk-local window-order row -> image-order row
__device__ __forceinline__ int win2img(int r) {
    int b = r >> 12;
    int w = (r >> 6) & 63;
    int t = r & 63;
    int img = (((w >> 3) << 3) + (t >> 3)) * 64 + ((w & 7) << 3) + (t & 7);
    return (b << 12) + img;
}

__device__ __forceinline__ u16x8 cvt8(const float* src) {
    float4 a = *(const float4*)src;
    float4 b = *(const float4*)(src + 4);
    u16x8 t;
    t[0] = f2bf(a.x); t[1] = f2bf(a.y); t[2] = f2bf(a.z); t[3] = f2bf(a.w);
    t[4] = f2bf(b.x); t[5] = f2bf(b.y); t[6] = f2bf(b.z); t[7] = f2bf(b.w);
    return t;
}

__global__ __launch_bounds__(256)
void conv_f2b(const float* __restrict__ in, u16* __restrict__ out, int n8) {
    int u = blockIdx.x * 256 + threadIdx.x;
    if (u >= n8) return;
    *(u16x8*)(out + (size_t)u * 8) = cvt8(in + (size_t)u * 8);
}

__global__ __launch_bounds__(256)
void conv_permute_x(const float* __restrict__ x, u16* __restrict__ xw) {
    int u = blockIdx.x * 256 + threadIdx.x;   // unit = 8 elems
    int r = u >> 6;                           // window-order row
    int c = (u & 63) << 3;
    int g = win2img(r);
    *(u16x8*)(xw + (size_t)r * 512 + c) = cvt8(x + (size_t)g * 512 + c);
}

// ---- 8-phase 256x256 GEMM, BK=64, 8 waves (2M x 4N), 128 KiB LDS ----
// C[M x Nfull] = A[M x 512]bf16 @ Wt[Nfull x 512]bf16^T + bias(f32).
// LDS layout: buf*65536 + op(A=0,B=32768) + row*128 + swz(colbyte),
// swz: colbyte ^= (row&7)<<4 (T2). global_load_lds dest is linear; the
// inverse swizzle is folded into the per-lane GLOBAL source column.
template<bool PERM_OUT, bool OUT_F32>
__global__ __launch_bounds__(512, 1)
void gemm8p(const u16* __restrict__ A, const u16* __restrict__ Wt,
            const float* __restrict__ bias, void* __restrict__ C,
            int NB, int Nfull)
{
    __shared__ char lds[131072];

    const int nwg = gridDim.x;            // % 8 == 0
    const int q   = nwg >> 3;
    const int wg  = ((int)blockIdx.x & 7) * q + ((int)blockIdx.x >> 3);
    const int m0  = (wg / NB) * 256;
    const int n0  = (wg % NB) * 256;

    const int tid  = threadIdx.x;
    const int lane = tid & 63;
    const int wv   = tid >> 6;
    const int wm128 = (wv >> 2) << 7;     // wave A-row base (0/128)
    const int wn64  = (wv & 3) << 6;      // wave B-row base (0..192)
    const int lr = lane & 15;
    const int lg = lane >> 4;

    // staging: thread covers rows srow, srow+64 of a 128-row half-tile
    const int srow = tid >> 3;                               // 0..63
    const int gcol = (((tid & 7) ^ (srow & 7)) << 4);        // pre-swizzled src col (bytes)
    const char* Ag = (const char*)A + (((size_t)(m0 + srow)) << 10) + gcol;
    const char* Bg = (const char*)Wt + (((size_t)(n0 + srow)) << 10) + gcol;
    const u32 stb = (u32)tid << 4;

    // frag reads
    const int colx = (lr & 7) << 4;                          // read-side xor
    const u32 aro = (u32)(wm128 + lr) << 7;                  // + mi*2048
    const u32 bro = (u32)(wn64 + lr) << 7;                   // + ni*2048

    f32x4 acc[8][4] = {};
    u16x8 af[4], bf[4];

#define STG(buf, OP, h, kt) do {                                              \
    const char* g_ = (OP) ? Bg : Ag;                                          \
    char* d_ = lds + (buf) * 65536 + (OP) * 32768 + (h) * 16384 + stb;        \
    gload16(g_ + ((size_t)((h) * 128) << 10) + ((kt) << 7), d_);              \
    gload16(g_ + ((size_t)((h) * 128 + 64) << 10) + ((kt) << 7), d_ + 8192);  \
} while (0)

#define RDA(buf, h, s) do {                                                   \
    _Pragma("unroll") for (int j_ = 0; j_ < 4; ++j_)                          \
        af[j_] = *(const u16x8*)(lds + (buf) * 65536 + aro                    \
                   + (((h) * 4 + j_) << 11) + ((((s) << 6) + (lg << 4)) ^ colx)); \
} while (0)

#define RDB(buf, s) do {                                                      \
    _Pragma("unroll") for (int n_ = 0; n_ < 4; ++n_)                          \
        bf[n_] = *(const u16x8*)(lds + (buf) * 65536 + 32768 + bro            \
                   + (n_ << 11) + ((((s) << 6) + (lg << 4)) ^ colx));         \
} while (0)

#define MM16(h) do {                                                          \
    __builtin_amdgcn_s_setprio(1);                                            \
    _Pragma("unroll") for (int j_ = 0; j_ < 4; ++j_)                          \
        _Pragma("unroll") for (int n_ = 0; n_ < 4; ++n_)                      \
            acc[(h) * 4 + j_][n_] = MFMA(af[j_], bf[n_], acc[(h) * 4 + j_][n_]); \
    __builtin_amdgcn_s_setprio(0);                                            \
} while (0)

#define BAR() __builtin_amdgcn_s_barrier()
#define LGK0() do { asm volatile("s_waitcnt lgkmcnt(0)" ::: "memory");        \
                    __builtin_amdgcn_sched_barrier(0); } while (0)

    // prologue: tile 0 -> buf0
    STG(0, 0, 0, 0); STG(0, 0, 1, 0); STG(0, 1, 0, 0); STG(0, 1, 1, 0);
    __syncthreads();

#pragma unroll
    for (int it = 0; it < 4; ++it) {
        const int t1 = 2 * it + 1, t2 = 2 * it + 2;
        // ---- group A: compute tile 2it (buf0), stage t1 -> buf1 ----
        // ph1
        RDA(0, 0, 0); RDB(0, 0);
        STG(1, 0, 0, t1); STG(1, 1, 0, t1);
        BAR(); LGK0(); MM16(0); BAR();
        // ph2
        RDA(0, 1, 0);
        STG(1, 0, 1, t1); STG(1, 1, 1, t1);
        BAR(); LGK0(); MM16(1); BAR();
        // ph3
        RDA(0, 0, 1); RDB(0, 1);
        BAR(); LGK0(); MM16(0); BAR();
        // ph4
        RDA(0, 1, 1);
        BAR(); LGK0(); MM16(1);
        __syncthreads();                 // drain: t1 landed, buf0 reads done
        // ---- group B: compute tile 2it+1 (buf1), stage t2 -> buf0 ----
        // ph5
        RDA(1, 0, 0); RDB(1, 0);
        if (it < 3) { STG(0, 0, 0, t2); STG(0, 1, 0, t2); }
        BAR(); LGK0(); MM16(0); BAR();
        // ph6
        RDA(1, 1, 0);
        if (it < 3) { STG(0, 0, 1, t2); STG(0, 1, 1, t2); }
        BAR(); LGK0(); MM16(1); BAR();
        // ph7
        RDA(1, 0, 1); RDB(1, 1);
        BAR(); LGK0(); MM16(0); BAR();
        // ph8
        RDA(1, 1, 1);
        BAR(); LGK0(); MM16(1);
        __syncthreads();                 // drain: t2 landed, buf1 reads done
    }

#undef STG
#undef RDA
#undef RDB
#undef MM16
#undef BAR
#undef LGK0

    // epilogue
#pragma unroll
    for (int ni = 0; ni < 4; ++ni) {
        const int col = n0 + wn64 + ni * 16 + lr;
        const float bv = bias[col];
#pragma unroll
        for (int mi = 0; mi < 8; ++mi) {
#pragma unroll
            for (int r = 0; r < 4; ++r) {
                int gr = m0 + wm128 + mi * 16 + lg * 4 + r;
                if (PERM_OUT) gr = win2img(gr);
                const float v = acc[mi][ni][r] + bv;
                if constexpr (OUT_F32)
                    ((float*)C)[(size_t)gr * Nfull + col] = v;
                else
                    ((u16*)C)[(size_t)gr * Nfull + col] = f2bf(v);
            }
        }
    }
}

// Attention: one block per window (64 tokens). 4 waves x 4 heads each.
__global__ __launch_bounds__(256, 2)
void attn_kernel(const u16* __restrict__ qkv, const float* __restrict__ mask,
                 u16* __restrict__ attn_out)
{
    __shared__ u16 sP[4][64][72];

    const int tid  = threadIdx.x;
    const int lane = tid & 63;
    const int wv   = tid >> 6;
    const int lr   = lane & 15;
    const int lg   = lane >> 4;
    const int win  = blockIdx.x;
    const int wib  = win & 63;
    const size_t rb = (size_t)win * 64;
    const float* maskp = mask + (size_t)wib * 64 * 64;
    const float scale = 0.17677669529663687f;   // 32^-0.5

    for (int hi = 0; hi < 4; ++hi) {
        const int h = hi * 4 + wv;
        const size_t hoff = (size_t)h * 32;

        u16x8 qf[4], kf[4];
#pragma unroll
        for (int mt = 0; mt < 4; ++mt) {
            const u16* rowp = qkv + (rb + mt * 16 + lr) * 1536 + hoff + lg * 8;
            qf[mt] = *(const u16x8*)rowp;
            kf[mt] = *(const u16x8*)(rowp + 512);
        }
        f32x4 s[4][4] = {};
#pragma unroll
        for (int mi = 0; mi < 4; ++mi)
#pragma unroll
            for (int ni = 0; ni < 4; ++ni)
                s[mi][ni] = MFMA(qf[mi], kf[ni], s[mi][ni]);

        float rsum[4][4];
#pragma unroll
        for (int mi = 0; mi < 4; ++mi) {
#pragma unroll
            for (int r = 0; r < 4; ++r) {
                const int qrow = mi * 16 + lg * 4 + r;
                float vv[4];
                float mx = -1e30f;
#pragma unroll
                for (int ni = 0; ni < 4; ++ni) {
                    const int kcol = ni * 16 + lr;
                    float v = s[mi][ni][r] * scale + maskp[qrow * 64 + kcol];
                    vv[ni] = v;
                    mx = fmaxf(mx, v);
                }
#pragma unroll
                for (int mk = 1; mk <= 8; mk <<= 1)
                    mx = fmaxf(mx, __shfl_xor(mx, mk, 64));
                float sum = 0.f;
#pragma unroll
                for (int ni = 0; ni < 4; ++ni) {
                    float p = __expf(vv[ni] - mx);
                    sum += p;
                    s[mi][ni][r] = p;
                }
#pragma unroll
                for (int mk = 1; mk <= 8; mk <<= 1)
                    sum += __shfl_xor(sum, mk, 64);
                rsum[mi][r] = sum;
            }
        }

        __syncthreads();
#pragma unroll
        for (int mi = 0; mi < 4; ++mi)
#pragma unroll
            for (int ni = 0; ni < 4; ++ni)
#pragma unroll
                for (int r = 0; r < 4; ++r)
                    sP[wv][mi * 16 + lg * 4 + r][ni * 16 + lr] = f2bf(s[mi][ni][r]);
        __syncthreads();

        u16x8 pf[4][2];
#pragma unroll
        for (int mt = 0; mt < 4; ++mt)
#pragma unroll
            for (int k2 = 0; k2 < 2; ++k2)
                pf[mt][k2] = *(const u16x8*)&sP[wv][mt * 16 + lr][k2 * 32 + lg * 8];

        u16x8 vf[2][2];
#pragma unroll
        for (int k2 = 0; k2 < 2; ++k2)
#pragma unroll
            for (int nt = 0; nt < 2; ++nt) {
                const u16* vp = qkv + (rb + k2 * 32 + lg * 8) * 1536 + 1024 + hoff + nt * 16 + lr;
                u16x8 tmp;
#pragma unroll
                for (int j = 0; j < 8; ++j) tmp[j] = vp[(size_t)j * 1536];
                vf[k2][nt] = tmp;
            }

        f32x4 o[4][2] = {};
#pragma unroll
        for (int mt = 0; mt < 4; ++mt)
#pragma unroll
            for (int k2 = 0; k2 < 2; ++k2)
#pragma unroll
                for (int nt = 0; nt < 2; ++nt)
                    o[mt][nt] = MFMA(pf[mt][k2], vf[k2][nt], o[mt][nt]);

#pragma unroll
        for (int mt = 0; mt < 4; ++mt)
#pragma unroll
            for (int nt = 0; nt < 2; ++nt)
#pragma unroll
                for (int r = 0; r < 4; ++r) {
                    const int row = mt * 16 + lg * 4 + r;
                    const int d = nt * 16 + lr;
                    attn_out[(rb + row) * 512 + hoff + d] =
                        f2bf(o[mt][nt][r] / rsum[mt][r]);
                }
    }
}

extern "C" void kernel_launch(void* const* d_in, const int* in_sizes, int n_in,
                              void* d_out, int out_size, void* d_ws, size_t ws_size,
                              hipStream_t stream)
{
    const float* x      = (const float*)d_in[0];
    const float* qkv_w  = (const float*)d_in[1];
    const float* qkv_b  = (const float*)d_in[2];
    const float* proj_w = (const float*)d_in[3];
    const float* proj_b = (const float*)d_in[4];
    const float* mask   = (const float*)d_in[5];
    float* out = (float*)d_out;

    const size_t WQKV  = 1536ull * 512;
    const size_t WPROJ = 512ull * 512;

    u16* wq = (u16*)d_ws;
    u16* wp = wq + WQKV;
    u16* chunk = wp + WPROJ;

    const size_t xwPB  = 4096ull * 512;
    const size_t qkvPB = 4096ull * 1536;
    const size_t attPB = 4096ull * 512;
    const size_t perBatchBytes = (xwPB + qkvPB + attPB) * 2;

    size_t avail = ws_size - (WQKV + WPROJ) * 2;
    int Bc = (int)(avail / perBatchBytes);
    if (Bc > 16) Bc = 16;
    if (Bc < 1) Bc = 1;

    u16* xw_ws  = chunk;
    u16* qkv_ws = xw_ws + (size_t)Bc * xwPB;
    u16* att_ws = qkv_ws + (size_t)Bc * qkvPB;

    conv_f2b<<<dim3((WQKV / 8 + 255) / 256), 256, 0, stream>>>(qkv_w, wq, (int)(WQKV / 8));
    conv_f2b<<<dim3((WPROJ / 8 + 255) / 256), 256, 0, stream>>>(proj_w, wp, (int)(WPROJ / 8));

    for (int b0 = 0; b0 < 16; b0 += Bc) {
        const int bc = (16 - b0) < Bc ? (16 - b0) : Bc;
        const float* xc = x + (size_t)b0 * 4096 * 512;
        float* outc = out + (size_t)b0 * 4096 * 512;

        conv_permute_x<<<dim3(bc * 1024), 256, 0, stream>>>(xc, xw_ws);
        // QKV: M = bc*4096, N = 1536 -> grid = (bc*16) * 6, N-fastest decode
        gemm8p<false, false><<<dim3(bc * 16 * 6), 512, 0, stream>>>(
            xw_ws, wq, qkv_b, qkv_ws, 6, 1536);
        attn_kernel<<<dim3(bc * 64), 256, 0, stream>>>(qkv_ws, mask, att_ws);
        // proj: N = 512 -> grid = (bc*16) * 2
        gemm8p<true, true><<<dim3(bc * 16 * 2), 512, 0, stream>>>(
            att_ws, wp, proj_b, outc, 2, 512);
    }
}